// Round 4
// baseline (461.075 us; speedup 1.0000x reference)
//
#include <hip/hip_runtime.h>
#include <math.h>

// HierarchicalRouter: x[32768][2048] fp32, W1[8][2048], W2[8][2048].
// Per token: 16 dots -> top2(groups) x top2(experts) -> 4 global indices
// (g*8+e) + softmax over the 4 combined (sum) scores.
// Output buffer (float32 throughout): [0,131072)      = topk_idx as floats
//                                     [131072,262144) = softmax weights
//
// R4 shape: wave = 4 groups x 16 lanes, 2 tokens per group (8 tokens/wave).
// acc[16][2]=32 VGPRs -> ~100 total -> 4 waves/SIMD (launch_bounds 256,4).
// 4096 waves / 1024 blocks = 4 blocks/CU. x loads nontemporal (stream once,
// don't evict the hot 128 KB weight set from L2).

#define D       2048
#define NTOK    32768
#define IDX_REG 131072   // NTOK*4, start of weights region

typedef float f4 __attribute__((ext_vector_type(4)));  // native vec: nt-load ok

template <int T>
__device__ __forceinline__ void load_sc(const float (&acc)[16][2], float (&sc)[16]) {
#pragma unroll
    for (int k = 0; k < 16; ++k) sc[k] = acc[k][T];
}

__global__ __launch_bounds__(256, 4) void router_kernel(
    const float* __restrict__ x,
    const float* __restrict__ W1,
    const float* __restrict__ W2,
    float* __restrict__ out)
{
    const int lane = threadIdx.x & 63;
    const int wave = (blockIdx.x << 2) | (threadIdx.x >> 6);   // 0..4095
    const int g    = lane >> 4;                                // group 0..3
    const int j    = lane & 15;                                // lane in group
    const int tok_base = wave * 8 + g * 2;                     // 2 tokens/group

    float acc[16][2];   // [expert_slot][token]
#pragma unroll
    for (int k = 0; k < 16; ++k) { acc[k][0] = 0.f; acc[k][1] = 0.f; }

    const float* xbase = x + (size_t)tok_base * D + (j << 2);

#pragma unroll 2
    for (int s = 0; s < 32; ++s) {
        const int d = s * 64 + (j << 2);

        f4 xv[2];
        xv[0] = __builtin_nontemporal_load((const f4*)(xbase + s * 64));
        xv[1] = __builtin_nontemporal_load((const f4*)(xbase + D + s * 64));

        // W1 half (slots 0..7); wv[8] reused for both halves to cap VGPRs.
        f4 wv[8];
#pragma unroll
        for (int k = 0; k < 8; ++k)
            wv[k] = *(const f4*)(W1 + k * D + d);
#pragma unroll
        for (int k = 0; k < 8; ++k)
#pragma unroll
            for (int t = 0; t < 2; ++t) {
                acc[k][t] = fmaf(wv[k].x, xv[t].x, acc[k][t]);
                acc[k][t] = fmaf(wv[k].y, xv[t].y, acc[k][t]);
                acc[k][t] = fmaf(wv[k].z, xv[t].z, acc[k][t]);
                acc[k][t] = fmaf(wv[k].w, xv[t].w, acc[k][t]);
            }

        // W2 half (slots 8..15)
#pragma unroll
        for (int k = 0; k < 8; ++k)
            wv[k] = *(const f4*)(W2 + k * D + d);
#pragma unroll
        for (int k = 0; k < 8; ++k)
#pragma unroll
            for (int t = 0; t < 2; ++t) {
                acc[8 + k][t] = fmaf(wv[k].x, xv[t].x, acc[8 + k][t]);
                acc[8 + k][t] = fmaf(wv[k].y, xv[t].y, acc[8 + k][t]);
                acc[8 + k][t] = fmaf(wv[k].z, xv[t].z, acc[8 + k][t]);
                acc[8 + k][t] = fmaf(wv[k].w, xv[t].w, acc[8 + k][t]);
            }
    }

    // Reduce across the 16 lanes of each group (xor butterfly stays in-group).
#pragma unroll
    for (int m = 1; m <= 8; m <<= 1)
#pragma unroll
        for (int k = 0; k < 16; ++k)
#pragma unroll
            for (int t = 0; t < 2; ++t)
                acc[k][t] += __shfl_xor(acc[k][t], m, 64);

    // Lanes 0..1 of each group finish one token each (compile-time column).
    if (j < 2) {
        float sc[16];
        if (j == 0) load_sc<0>(acc, sc);
        else        load_sc<1>(acc, sc);

        const int token = tok_base + j;

        // top2 of group scores (earlier index wins ties, like lax.top_k)
        float bg0 = sc[0]; int gi0 = 0; float bg1 = -INFINITY; int gi1 = 0;
#pragma unroll
        for (int k = 1; k < 8; ++k) {
            float v = sc[k];
            if (v > bg0) { bg1 = bg0; gi1 = gi0; bg0 = v; gi0 = k; }
            else if (v > bg1) { bg1 = v; gi1 = k; }
        }
        // top2 of expert scores
        float be0 = sc[8]; int ei0 = 0; float be1 = -INFINITY; int ei1 = 0;
#pragma unroll
        for (int k = 1; k < 8; ++k) {
            float v = sc[8 + k];
            if (v > be0) { be1 = be0; ei1 = ei0; be0 = v; ei0 = k; }
            else if (v > be1) { be1 = v; ei1 = k; }
        }

        // combined scores; c0 = bg0+be0 is the max by construction
        float c0 = bg0 + be0, c1 = bg0 + be1, c2 = bg1 + be0, c3 = bg1 + be1;
        float e0 = 1.f;
        float e1 = __expf(c1 - c0);
        float e2 = __expf(c2 - c0);
        float e3 = __expf(c3 - c0);
        float inv = 1.f / (e0 + e1 + e2 + e3);

        float4 idxv = make_float4((float)(gi0 * 8 + ei0), (float)(gi0 * 8 + ei1),
                                  (float)(gi1 * 8 + ei0), (float)(gi1 * 8 + ei1));
        float4 wout = make_float4(e0 * inv, e1 * inv, e2 * inv, e3 * inv);

        *(float4*)(out + (size_t)token * 4)           = idxv;
        *(float4*)(out + IDX_REG + (size_t)token * 4) = wout;
    }
}

extern "C" void kernel_launch(void* const* d_in, const int* in_sizes, int n_in,
                              void* d_out, int out_size, void* d_ws, size_t ws_size,
                              hipStream_t stream) {
    const float* x  = (const float*)d_in[0];
    const float* W1 = (const float*)d_in[1];
    const float* W2 = (const float*)d_in[2];
    float* out = (float*)d_out;
    // 32768 tokens / 8 tokens-per-wave = 4096 waves = 1024 blocks of 256 thr
    dim3 grid(1024), block(256);
    hipLaunchKernelGGL(router_kernel, grid, block, 0, stream, x, W1, W2, out);
}

// Round 5
// 342.579 us; speedup vs baseline: 1.3459x; 1.3459x over previous
//
#include <hip/hip_runtime.h>
#include <math.h>

// HierarchicalRouter: x[32768][2048] fp32, W1[8][2048], W2[8][2048].
// Per token: 16 dots -> top2(groups) x top2(experts) -> 4 global indices
// (g*8+e) + softmax over the 4 combined (sum) scores.
// Output buffer (float32 throughout): [0,131072)      = topk_idx as floats
//                                     [131072,262144) = softmax weights
//
// R5: weights staged in LDS (128 KB/block) -> inner loop has only 4 global
// x-loads + 16 ds_read_b128 per step. Block = 512 thr (8 waves), 1 block/CU
// (LDS-forced), 128 tokens/block, 256 blocks exactly. launch_bounds(512,2)
// keeps the VGPR cap at 256 so a full iteration + prefetch stays in regs
// (R4 lesson: a 64-VGPR allocation serializes the load stream).

#define D       2048
#define NTOK    32768
#define IDX_REG 131072   // NTOK*4, start of weights region

typedef float f4 __attribute__((ext_vector_type(4)));

template <int T>
__device__ __forceinline__ void load_sc(const float (&acc)[16][4], float (&sc)[16]) {
#pragma unroll
    for (int k = 0; k < 16; ++k) sc[k] = acc[k][T];
}

__global__ __launch_bounds__(512, 2) void router_kernel(
    const float* __restrict__ x,
    const float* __restrict__ W1,
    const float* __restrict__ W2,
    float* __restrict__ out)
{
    __shared__ float w_lds[32768];   // [row 0..15][2048], rows 8..15 = W2

    const int tid  = threadIdx.x;
    const int lane = tid & 63;
    const int g    = lane >> 4;                 // group 0..3
    const int j    = lane & 15;                 // lane in group
    const int wave = (blockIdx.x << 3) | (tid >> 6);   // 0..2047
    const int tok_base = wave * 16 + g * 4;     // 4 tokens/group

    // Stage W1+W2 into LDS (32768 floats = 8192 f4; 16 f4 per thread).
    {
        f4* lds4 = (f4*)w_lds;
        const f4* w1v = (const f4*)W1;
        const f4* w2v = (const f4*)W2;
#pragma unroll
        for (int i = 0; i < 8; ++i) {
            int idx = tid + i * 512;
            lds4[idx]        = w1v[idx];
            lds4[4096 + idx] = w2v[idx];
        }
    }
    __syncthreads();

    float acc[16][4];   // [expert_slot][token]
#pragma unroll
    for (int k = 0; k < 16; ++k)
#pragma unroll
        for (int t = 0; t < 4; ++t) acc[k][t] = 0.f;

    const float* xbase = x + (size_t)tok_base * D + (j << 2);

#pragma unroll 2
    for (int s = 0; s < 32; ++s) {
        const int d = s * 64 + (j << 2);

        f4 xv[4];
#pragma unroll
        for (int t = 0; t < 4; ++t)
            xv[t] = __builtin_nontemporal_load((const f4*)(xbase + t * D + s * 64));

        f4 wv[16];
#pragma unroll
        for (int k = 0; k < 16; ++k)
            wv[k] = *(const f4*)(w_lds + k * D + d);

#pragma unroll
        for (int k = 0; k < 16; ++k)
#pragma unroll
            for (int t = 0; t < 4; ++t) {
                acc[k][t] = fmaf(wv[k].x, xv[t].x, acc[k][t]);
                acc[k][t] = fmaf(wv[k].y, xv[t].y, acc[k][t]);
                acc[k][t] = fmaf(wv[k].z, xv[t].z, acc[k][t]);
                acc[k][t] = fmaf(wv[k].w, xv[t].w, acc[k][t]);
            }
    }

    // Reduce across the 16 lanes of each group (xor butterfly stays in-group).
#pragma unroll
    for (int m = 1; m <= 8; m <<= 1)
#pragma unroll
        for (int k = 0; k < 16; ++k)
#pragma unroll
            for (int t = 0; t < 4; ++t)
                acc[k][t] += __shfl_xor(acc[k][t], m, 64);

    // Lanes 0..3 of each group finish one token each (compile-time column).
    if (j < 4) {
        float sc[16];
        if      (j == 0) load_sc<0>(acc, sc);
        else if (j == 1) load_sc<1>(acc, sc);
        else if (j == 2) load_sc<2>(acc, sc);
        else             load_sc<3>(acc, sc);

        const int token = tok_base + j;

        // top2 of group scores (earlier index wins ties, like lax.top_k)
        float bg0 = sc[0]; int gi0 = 0; float bg1 = -INFINITY; int gi1 = 0;
#pragma unroll
        for (int k = 1; k < 8; ++k) {
            float v = sc[k];
            if (v > bg0) { bg1 = bg0; gi1 = gi0; bg0 = v; gi0 = k; }
            else if (v > bg1) { bg1 = v; gi1 = k; }
        }
        // top2 of expert scores
        float be0 = sc[8]; int ei0 = 0; float be1 = -INFINITY; int ei1 = 0;
#pragma unroll
        for (int k = 1; k < 8; ++k) {
            float v = sc[8 + k];
            if (v > be0) { be1 = be0; ei1 = ei0; be0 = v; ei0 = k; }
            else if (v > be1) { be1 = v; ei1 = k; }
        }

        // combined scores; c0 = bg0+be0 is the max by construction
        float c0 = bg0 + be0, c1 = bg0 + be1, c2 = bg1 + be0, c3 = bg1 + be1;
        float e0 = 1.f;
        float e1 = __expf(c1 - c0);
        float e2 = __expf(c2 - c0);
        float e3 = __expf(c3 - c0);
        float inv = 1.f / (e0 + e1 + e2 + e3);

        float4 idxv = make_float4((float)(gi0 * 8 + ei0), (float)(gi0 * 8 + ei1),
                                  (float)(gi1 * 8 + ei0), (float)(gi1 * 8 + ei1));
        float4 wout = make_float4(e0 * inv, e1 * inv, e2 * inv, e3 * inv);

        *(float4*)(out + (size_t)token * 4)           = idxv;
        *(float4*)(out + IDX_REG + (size_t)token * 4) = wout;
    }
}

extern "C" void kernel_launch(void* const* d_in, const int* in_sizes, int n_in,
                              void* d_out, int out_size, void* d_ws, size_t ws_size,
                              hipStream_t stream) {
    const float* x  = (const float*)d_in[0];
    const float* W1 = (const float*)d_in[1];
    const float* W2 = (const float*)d_in[2];
    float* out = (float*)d_out;
    // 32768 tokens / 128 tokens-per-block = 256 blocks of 512 threads
    dim3 grid(256), block(512);
    hipLaunchKernelGGL(router_kernel, grid, block, 0, stream, x, W1, W2, out);
}